// Round 1
// baseline (71.338 us; speedup 1.0000x reference)
//
#include <hip/hip_runtime.h>

// FSQ: z (4,16,256,64) fp32, bins (64,256) fp32 (uniform linspace(-1,1,256) per row).
// Outputs flat fp32: [loss(1), z_q(1048576), bin_indices_as_float(1048576)]
// loss = 2 * mean((z - zq)^2)   (commitment + BETA*codebook, BETA=1, identical forward)

#define N_ELEM (4 * 16 * 256 * 64) // 1048576
#define D_LAT 64
#define NBINS 256
#define BLOCK 256
#define GRID (N_ELEM / BLOCK) // 4096

__global__ __launch_bounds__(BLOCK) void fsq_main(const float* __restrict__ z,
                                                  const float* __restrict__ bins,
                                                  float* __restrict__ out,
                                                  float* __restrict__ partial) {
    const int i = blockIdx.x * BLOCK + threadIdx.x;
    const float v = z[i];
    const int d = i & (D_LAT - 1);
    const float* brow = bins + d * NBINS;

    // Candidate nearest-bin index via uniform-spacing formula, clamped.
    float t = (v + 1.0f) * 127.5f;
    int j = (int)floorf(t + 0.5f);
    j = min(max(j, 0), NBINS - 1);

    // Refine with actual bin values; tie-break to LOWEST index (argmin semantics).
    int best = j;
    float bv = brow[j];
    float bd = fabsf(v - bv);
    if (j > 0) {
        float b0 = brow[j - 1];
        float d0 = fabsf(v - b0);
        if (d0 <= bd) { best = j - 1; bv = b0; bd = d0; } // <= : lower index wins tie
    }
    if (j + 1 < NBINS) {
        float b1 = brow[j + 1];
        float d1 = fabsf(v - b1);
        if (d1 < bd) { best = j + 1; bv = b1; bd = d1; } // strict < : lower index wins tie
    }

    // z_q (== zq forward) and index-as-float
    out[1 + i] = bv;
    out[1 + N_ELEM + i] = (float)best;

    // squared error, block reduction -> partial sums
    float diff = v - bv;
    float s = diff * diff;
#pragma unroll
    for (int off = 32; off > 0; off >>= 1) s += __shfl_down(s, off, 64);

    __shared__ float lds[BLOCK / 64];
    const int lane = threadIdx.x & 63;
    const int wave = threadIdx.x >> 6;
    if (lane == 0) lds[wave] = s;
    __syncthreads();
    if (threadIdx.x == 0) {
        float tot = lds[0] + lds[1] + lds[2] + lds[3];
        partial[blockIdx.x] = tot;
    }
}

__global__ __launch_bounds__(BLOCK) void fsq_reduce(const float* __restrict__ partial,
                                                    float* __restrict__ out) {
    float s = 0.0f;
    for (int i = threadIdx.x; i < GRID; i += BLOCK) s += partial[i];
#pragma unroll
    for (int off = 32; off > 0; off >>= 1) s += __shfl_down(s, off, 64);

    __shared__ float lds[BLOCK / 64];
    const int lane = threadIdx.x & 63;
    const int wave = threadIdx.x >> 6;
    if (lane == 0) lds[wave] = s;
    __syncthreads();
    if (threadIdx.x == 0) {
        float tot = lds[0] + lds[1] + lds[2] + lds[3];
        out[0] = 2.0f * tot / (float)N_ELEM; // (1 + BETA) * mean
    }
}

extern "C" void kernel_launch(void* const* d_in, const int* in_sizes, int n_in,
                              void* d_out, int out_size, void* d_ws, size_t ws_size,
                              hipStream_t stream) {
    const float* z = (const float*)d_in[0];
    const float* bins = (const float*)d_in[1];
    float* out = (float*)d_out;
    float* partial = (float*)d_ws; // 4096 floats, fully written before read

    fsq_main<<<GRID, BLOCK, 0, stream>>>(z, bins, out, partial);
    fsq_reduce<<<1, BLOCK, 0, stream>>>(partial, out);
}